// Round 22
// baseline (639.938 us; speedup 1.0000x reference)
//
#include <hip/hip_runtime.h>
#include <hip/hip_bf16.h>
#include <cstdint>
#include <cstddef>

#define DEV __device__ __forceinline__

namespace {

constexpr int S    = 2048;
constexpr int D    = 512;
constexpr int H    = 8;
constexpr int DH   = 64;
constexpr int NL   = 6;
constexpr int MLPD = 2048;
constexpr int VOC  = 256;
constexpr int QS   = 1536;   // fused qkv row stride
constexpr float EPSF = 1e-6f;

typedef unsigned short u16;
typedef __attribute__((ext_vector_type(8))) short s8v;   // 8 x bf16 (4 VGPR)
typedef __attribute__((ext_vector_type(4))) float f4v;   // MFMA accum

DEV float u2f(u16 u){
  union { unsigned int i; float f; } t; t.i = ((unsigned int)u) << 16; return t.f;
}
DEV short bfr(float f){
  __hip_bfloat16 h = __float2bfloat16(f);
  short s; __builtin_memcpy(&s, &h, 2); return s;
}
// gelu_tanh(x) = 0.5x(1+tanh(z)) == x / (1 + e^{-2z}) exactly; __expf ~1ulp.
DEV float gelu_fast(float x){
  float z = 0.7978845608028654f * (x + 0.044715f * x * x * x);
  return x / (1.f + __expf(-2.f * z));
}
DEV void gll16(const u16* gp, u16* lp){
  __builtin_amdgcn_global_load_lds(
      (const __attribute__((address_space(1))) unsigned int*)gp,
      (__attribute__((address_space(3))) unsigned int*)lp, 16, 0, 0);
}

// ---------------- embedding + positional --------------------------------------
__global__ void k_embed(const int* __restrict__ tokens, const float* __restrict__ emb,
                        const float* __restrict__ pos, float* __restrict__ x){
  int s = blockIdx.x;
  int tok = (s == 0) ? 0 : tokens[s - 1];
  if (tok < 0) tok = 0; if (tok >= VOC) tok = VOC - 1;
  const float* er = emb + (size_t)tok * D;
  const float* pr = pos + (size_t)s * D;
  float* xr = x + (size_t)s * D;
  for (int d = threadIdx.x; d < D; d += blockDim.x)
    xr[d] = er[d] + pr[d];
}

// ------- fused split-K-reduce + residual + layernorm --------------------------
template<int HASP>
__global__ __launch_bounds__(256)
void k_lnr(const float* __restrict__ P0, const float* __restrict__ P1,
           const float* __restrict__ bias, float* __restrict__ x,
           const float* __restrict__ sc, const float* __restrict__ bi,
           u16* __restrict__ out)
{
  int s = blockIdx.x * 4 + (threadIdx.x >> 6), t = threadIdx.x & 63;
  size_t base = (size_t)s * D;
  float v[8]; float sum = 0.f, sq = 0.f;
  #pragma unroll
  for (int e = 0; e < 8; ++e){
    int d = t + 64 * e;
    size_t idx = base + d;
    float xv = x[idx];
    if (HASP){
      float bv = bias ? bias[d] : 0.f;
      xv += P0[idx] + P1[idx] + bv;
      x[idx] = xv;
    }
    v[e] = xv; sum += xv; sq += xv * xv;
  }
  #pragma unroll
  for (int off = 32; off >= 1; off >>= 1){
    sum += __shfl_down(sum, off, 64);
    sq  += __shfl_down(sq,  off, 64);
  }
  sum = __shfl(sum, 0, 64); sq = __shfl(sq, 0, 64);
  float mu  = sum * (1.f / (float)D);
  float var = sq * (1.f / (float)D) - mu * mu;
  float r = rsqrtf(var + EPSF);
  u16* orow = out + base;
  #pragma unroll
  for (int e = 0; e < 8; ++e){
    int d = t + 64 * e;
    orow[d] = (u16)bfr((v[e] - mu) * r * sc[d] + bi[d]);
  }
}

// ---------------- weight transpose+convert: fp32 [R][C] -> bf16 [C][R] --------
__global__ __launch_bounds__(256)
void k_wt(const float* __restrict__ src, u16* __restrict__ dst, int R, int C,
          size_t sStr, size_t dStr){
  src += (size_t)blockIdx.z * sStr;
  dst += (size_t)blockIdx.z * dStr;
  __shared__ float tb[32][33];
  int c0 = blockIdx.x * 32, r0 = blockIdx.y * 32;
  int tc = threadIdx.x & 31, tr8 = threadIdx.x >> 5;
  #pragma unroll
  for (int rr = 0; rr < 32; rr += 8)
    tb[rr + tr8][tc] = src[(size_t)(r0 + rr + tr8) * C + c0 + tc];
  __syncthreads();
  #pragma unroll
  for (int rr = 0; rr < 32; rr += 8)
    dst[(size_t)(c0 + rr + tr8) * R + r0 + tc] = (u16)bfr(tb[tc][rr + tr8]);
}

// ---- batched 512x512 transpose: z in [0,24) = family(z/6: wq,wk,wv,wo) x layer
__global__ __launch_bounds__(256)
void k_wt4(const float* __restrict__ wq, const float* __restrict__ wk,
           const float* __restrict__ wv, const float* __restrict__ wo,
           u16* __restrict__ wqkvT, u16* __restrict__ woT)
{
  const size_t L512 = (size_t)512 * 512;
  int fam = blockIdx.z / 6, l = blockIdx.z % 6;
  const float* src;
  u16* dst;
  if (fam == 0){ src = wq + (size_t)l * L512; dst = wqkvT + (size_t)l * QS * 512; }
  else if (fam == 1){ src = wk + (size_t)l * L512; dst = wqkvT + (size_t)l * QS * 512 + 512 * 512; }
  else if (fam == 2){ src = wv + (size_t)l * L512; dst = wqkvT + (size_t)l * QS * 512 + 1024 * 512; }
  else { src = wo + (size_t)l * L512; dst = woT + (size_t)l * L512; }
  __shared__ float tb[32][33];
  int c0 = blockIdx.x * 32, r0 = blockIdx.y * 32;
  int tc = threadIdx.x & 31, tr8 = threadIdx.x >> 5;
  #pragma unroll
  for (int rr = 0; rr < 32; rr += 8)
    tb[rr + tr8][tc] = src[(size_t)(r0 + rr + tr8) * 512 + c0 + tc];
  __syncthreads();
  #pragma unroll
  for (int rr = 0; rr < 32; rr += 8)
    dst[(size_t)(c0 + rr + tr8) * 512 + r0 + tc] = (u16)bfr(tb[tc][rr + tr8]);
}

// ================= direct-from-global MFMA GEMM (verified r10/r11) ============
template<int FM, int FN, int MODE>
__global__ __launch_bounds__(64)
void k_gd(const u16* __restrict__ A, const u16* __restrict__ Bt,
          const float* __restrict__ bias, float* __restrict__ Cf,
          u16* __restrict__ Cb, int N, int K, float alpha)
{
  const int nx = gridDim.x;
  const int nwg = nx * gridDim.y;
  int wg = blockIdx.y * nx + blockIdx.x;
  wg = (wg & 7) * (nwg >> 3) + (wg >> 3);        // XCD swizzle (nwg % 8 == 0)
  const int m0 = (wg / nx) * (FM * 16), n0 = (wg % nx) * (FN * 16);
  const int lane = threadIdx.x, lr = lane & 15, lg = lane >> 4;
  const u16* ap = A  + (size_t)(m0 + lr) * K + lg * 8;
  const u16* bp = Bt + (size_t)(n0 + lr) * K + lg * 8;
  f4v acc[FM][FN] = {};
  #pragma unroll 4
  for (int k0 = 0; k0 < K; k0 += 32){
    s8v af[FM], bf[FN];
    #pragma unroll
    for (int fi = 0; fi < FM; ++fi)
      af[fi] = *reinterpret_cast<const s8v*>(ap + (size_t)fi * 16 * K + k0);
    #pragma unroll
    for (int fj = 0; fj < FN; ++fj)
      bf[fj] = *reinterpret_cast<const s8v*>(bp + (size_t)fj * 16 * K + k0);
    #pragma unroll
    for (int fi = 0; fi < FM; ++fi)
      #pragma unroll
      for (int fj = 0; fj < FN; ++fj)
        acc[fi][fj] = __builtin_amdgcn_mfma_f32_16x16x32_bf16(af[fi], bf[fj], acc[fi][fj], 0, 0, 0);
  }
  #pragma unroll
  for (int fi = 0; fi < FM; ++fi)
    #pragma unroll
    for (int fj = 0; fj < FN; ++fj)
      #pragma unroll
      for (int r = 0; r < 4; ++r){
        int row = m0 + fi * 16 + lg * 4 + r;
        int col = n0 + fj * 16 + lr;
        size_t idx = (size_t)row * N + col;
        float v = acc[fi][fj][r];
        if (MODE == 1)      Cb[idx] = (u16)bfr(gelu_fast(v + bias[col]));
        else if (MODE == 2) Cf[idx] += v + (bias ? bias[col] : 0.f);
        else if (MODE == 3) Cf[idx] = v + bias[col];
        else {
          float al = (col < 512) ? alpha : 1.f;
          Cb[idx] = (u16)bfr(v * al);
        }
      }
}

// ===== LDS-staged GEMM, tile 128(M)x64(N), 4 waves (2x2 of 64x32) =============
// (verified r19: chunk-XOR swizzle, 2 blocks/CU.) MODE 1: gelu epilogue.
template<int MODE>
__global__ __launch_bounds__(256)
void k_gs(const u16* __restrict__ A, const u16* __restrict__ Bt,
          const float* __restrict__ bias, u16* __restrict__ Cb,
          int N, int K)
{
  __shared__ __align__(16) u16 As[128 * 32];
  __shared__ __align__(16) u16 Bs[64 * 32];
  const int nx = gridDim.x;
  const int nwg = nx * gridDim.y;
  int wg = blockIdx.y * nx + blockIdx.x;
  wg = (wg & 7) * (nwg >> 3) + (wg >> 3);        // XCD swizzle (nwg % 8 == 0)
  const int m0 = (wg / nx) * 128, n0 = (wg % nx) * 64;
  const int w = threadIdx.x >> 6, lane = threadIdx.x & 63;
  const int lr = lane & 15, lg = lane >> 4;
  const int wr = w >> 1, wc = w & 1;
  const int srow = lane >> 2, scd = lane & 3;
  const int swA0 = ((srow) ^ (srow >> 2)) & 3;
  f4v acc[4][2] = {};
  for (int k0 = 0; k0 < K; k0 += 32){
    __syncthreads();
    #pragma unroll
    for (int j = w; j < 8; j += 4){
      int row = j * 16 + srow;
      int g = scd ^ swA0;
      gll16(A + (size_t)(m0 + row) * K + k0 + g * 8, As + j * 512);
    }
    {
      int row = w * 16 + srow;
      int g = scd ^ swA0;
      gll16(Bt + (size_t)(n0 + row) * K + k0 + g * 8, Bs + w * 512);
    }
    asm volatile("s_waitcnt vmcnt(0)" ::: "memory");
    __syncthreads();
    s8v af[4], bf[2];
    #pragma unroll
    for (int fi = 0; fi < 4; ++fi){
      int row = wr * 64 + fi * 16 + lr;
      int slot = lg ^ ((row ^ (row >> 2)) & 3);
      af[fi] = *reinterpret_cast<const s8v*>(As + row * 32 + slot * 8);
    }
    #pragma unroll
    for (int fj = 0; fj < 2; ++fj){
      int row = wc * 32 + fj * 16 + lr;
      int slot = lg ^ ((row ^ (row >> 2)) & 3);
      bf[fj] = *reinterpret_cast<const s8v*>(Bs + row * 32 + slot * 8);
    }
    #pragma unroll
    for (int fi = 0; fi < 4; ++fi)
      #pragma unroll
      for (int fj = 0; fj < 2; ++fj)
        acc[fi][fj] = __builtin_amdgcn_mfma_f32_16x16x32_bf16(af[fi], bf[fj], acc[fi][fj], 0, 0, 0);
  }
  #pragma unroll
  for (int fi = 0; fi < 4; ++fi)
    #pragma unroll
    for (int fj = 0; fj < 2; ++fj)
      #pragma unroll
      for (int r = 0; r < 4; ++r){
        int row = m0 + wr * 64 + fi * 16 + lg * 4 + r;
        int col = n0 + wc * 32 + fj * 16 + lr;
        float v = acc[fi][fj][r];
        if (MODE == 1) Cb[(size_t)row * N + col] = (u16)bfr(gelu_fast(v + bias[col]));
      }
}

// ===== staged qkv: k_gs body + verified MODE-4 epilogue (verified r20) ========
__global__ __launch_bounds__(256)
void k_gsq(const u16* __restrict__ A, const u16* __restrict__ Bt,
           u16* __restrict__ vt, u16* __restrict__ Cb, float alpha)
{
  constexpr int K = 512, N = QS;
  __shared__ __align__(16) u16 As[128 * 32];
  __shared__ __align__(16) u16 Bs[64 * 32];
  const int nx = gridDim.x;
  const int nwg = nx * gridDim.y;
  int wg = blockIdx.y * nx + blockIdx.x;
  wg = (wg & 7) * (nwg >> 3) + (wg >> 3);        // XCD swizzle (384 % 8 == 0)
  const int m0 = (wg / nx) * 128, n0 = (wg % nx) * 64;
  const int w = threadIdx.x >> 6, lane = threadIdx.x & 63;
  const int lr = lane & 15, lg = lane >> 4;
  const int wr = w >> 1, wc = w & 1;
  const int srow = lane >> 2, scd = lane & 3;
  const int swA0 = ((srow) ^ (srow >> 2)) & 3;
  f4v acc[4][2] = {};
  for (int k0 = 0; k0 < K; k0 += 32){
    __syncthreads();
    #pragma unroll
    for (int j = w; j < 8; j += 4){
      int row = j * 16 + srow;
      int g = scd ^ swA0;
      gll16(A + (size_t)(m0 + row) * K + k0 + g * 8, As + j * 512);
    }
    {
      int row = w * 16 + srow;
      int g = scd ^ swA0;
      gll16(Bt + (size_t)(n0 + row) * K + k0 + g * 8, Bs + w * 512);
    }
    asm volatile("s_waitcnt vmcnt(0)" ::: "memory");
    __syncthreads();
    s8v af[4], bf[2];
    #pragma unroll
    for (int fi = 0; fi < 4; ++fi){
      int row = wr * 64 + fi * 16 + lr;
      int slot = lg ^ ((row ^ (row >> 2)) & 3);
      af[fi] = *reinterpret_cast<const s8v*>(As + row * 32 + slot * 8);
    }
    #pragma unroll
    for (int fj = 0; fj < 2; ++fj){
      int row = wc * 32 + fj * 16 + lr;
      int slot = lg ^ ((row ^ (row >> 2)) & 3);
      bf[fj] = *reinterpret_cast<const s8v*>(Bs + row * 32 + slot * 8);
    }
    #pragma unroll
    for (int fi = 0; fi < 4; ++fi)
      #pragma unroll
      for (int fj = 0; fj < 2; ++fj)
        acc[fi][fj] = __builtin_amdgcn_mfma_f32_16x16x32_bf16(af[fi], bf[fj], acc[fi][fj], 0, 0, 0);
  }
  #pragma unroll
  for (int fi = 0; fi < 4; ++fi)
    #pragma unroll
    for (int fj = 0; fj < 2; ++fj)
      #pragma unroll
      for (int r = 0; r < 4; ++r){
        int row = m0 + wr * 64 + fi * 16 + lg * 4 + r;
        int col = n0 + wc * 32 + fj * 16 + lr;
        float v = acc[fi][fj][r];
        if (col < 512){
          Cb[(size_t)row * N + col] = (u16)bfr(v * alpha);
        } else if (col < 1024){
          Cb[(size_t)row * N + col] = (u16)bfr(v);
        } else {
          vt[(size_t)(col - 1024) * S + row] = (u16)bfr(v);   // V^T only
        }
      }
}

// ---- inter-block split-K variant (verified r11): fp32 partials ---------------
template<int FM, int FN>
__global__ __launch_bounds__(64)
void k_gds(const u16* __restrict__ A, const u16* __restrict__ Bt,
           float* __restrict__ P, int N, int K, int KC)
{
  const int nx = gridDim.x;
  const int nwg = nx * gridDim.y;
  const int M = gridDim.y * (FM * 16);
  int wg = blockIdx.y * nx + blockIdx.x;
  wg = (wg & 7) * (nwg >> 3) + (wg >> 3);        // XCD swizzle (nwg % 8 == 0)
  const int m0 = (wg / nx) * (FM * 16), n0 = (wg % nx) * (FN * 16);
  const int z = blockIdx.z;
  const int lane = threadIdx.x, lr = lane & 15, lg = lane >> 4;
  const u16* ap = A  + (size_t)(m0 + lr) * K + z * KC + lg * 8;
  const u16* bp = Bt + (size_t)(n0 + lr) * K + z * KC + lg * 8;
  P += (size_t)z * M * N;
  f4v acc[FM][FN] = {};
  #pragma unroll 4
  for (int k0 = 0; k0 < KC; k0 += 32){
    s8v af[FM], bf[FN];
    #pragma unroll
    for (int fi = 0; fi < FM; ++fi)
      af[fi] = *reinterpret_cast<const s8v*>(ap + (size_t)fi * 16 * K + k0);
    #pragma unroll
    for (int fj = 0; fj < FN; ++fj)
      bf[fj] = *reinterpret_cast<const s8v*>(bp + (size_t)fj * 16 * K + k0);
    #pragma unroll
    for (int fi = 0; fi < FM; ++fi)
      #pragma unroll
      for (int fj = 0; fj < FN; ++fj)
        acc[fi][fj] = __builtin_amdgcn_mfma_f32_16x16x32_bf16(af[fi], bf[fj], acc[fi][fj], 0, 0, 0);
  }
  #pragma unroll
  for (int fi = 0; fi < FM; ++fi)
    #pragma unroll
    for (int fj = 0; fj < FN; ++fj)
      #pragma unroll
      for (int r = 0; r < 4; ++r){
        int row = m0 + fi * 16 + lg * 4 + r;
        int col = n0 + fj * 16 + lr;
        P[(size_t)row * N + col] = acc[fi][fj][r];
      }
}

// -------- split-KV x4 flash attention: 4 waves per (head, 16 q-rows) ----------
// Wave w handles tiles tt = w, w+4, ... (interleaved). Waves 1-3 publish
// (m, l, o) via LDS; wave 0 performs 3 sequential deterministic flash merges
// then the epilogue. Dead rows compose (all m=-1e30 => l=0 => fallback).
__global__ __launch_bounds__(256)
void k_mattn(const u16* __restrict__ qp_, const u16* __restrict__ kp_,
             const u16* __restrict__ vt, const int* __restrict__ tokens,
             u16* __restrict__ ob)
{
  const int q0 = (gridDim.x - 1 - blockIdx.x) * 16;   // heavy-first
  const int h  = blockIdx.y;
  const int B  = q0 >> 7;
  const int w  = threadIdx.x >> 6;
  const int lane = threadIdx.x & 63, lr = lane & 15, lg = lane >> 4;

  __shared__ __align__(16) u16 Ps[4][16][40];
  __shared__ float Msh[3][64][4], Lsh[3][64][4], Osh[3][4][64][4];

  const u16* qrow = qp_ + (size_t)(q0 + lr) * QS + h * DH;
  s8v qf0 = *reinterpret_cast<const s8v*>(qrow + lg * 8);
  s8v qf1 = *reinterpret_cast<const s8v*>(qrow + 32 + lg * 8);

  f4v o0 = {}, o1 = {}, o2 = {}, o3 = {};
  float m[4] = {-1e30f, -1e30f, -1e30f, -1e30f};
  float l[4] = {0.f, 0.f, 0.f, 0.f};

  const int ntiles = B + ((q0 & 127) >> 5) + 1;

  for (int tt = w; tt < ntiles; tt += 4){
    int kbase; bool causal;
    if (tt < B){ kbase = tt * 128 + 96; causal = false; }
    else       { kbase = B * 128 + (tt - B) * 32; causal = (kbase + 31 > q0); }

    f4v s0 = {}, s1 = {};
    const u16* k0p = kp_ + (size_t)(kbase + lr) * QS + h * DH;
    const u16* k1p = kp_ + (size_t)(kbase + 16 + lr) * QS + h * DH;
    s8v kf;
    kf = *reinterpret_cast<const s8v*>(k0p + lg * 8);
    s0 = __builtin_amdgcn_mfma_f32_16x16x32_bf16(qf0, kf, s0, 0, 0, 0);
    kf = *reinterpret_cast<const s8v*>(k0p + 32 + lg * 8);
    s0 = __builtin_amdgcn_mfma_f32_16x16x32_bf16(qf1, kf, s0, 0, 0, 0);
    kf = *reinterpret_cast<const s8v*>(k1p + lg * 8);
    s1 = __builtin_amdgcn_mfma_f32_16x16x32_bf16(qf0, kf, s1, 0, 0, 0);
    kf = *reinterpret_cast<const s8v*>(k1p + 32 + lg * 8);
    s1 = __builtin_amdgcn_mfma_f32_16x16x32_bf16(qf1, kf, s1, 0, 0, 0);

    const int tok0 = tokens[kbase + lr] > 0;
    const int tok1 = tokens[kbase + 16 + lr] > 0;
    #pragma unroll
    for (int r = 0; r < 4; ++r){
      int qg = q0 + 4 * lg + r;
      float a0 = (tok0 && (!causal || kbase + lr <= qg))      ? s0[r] : -1e30f;
      float a1 = (tok1 && (!causal || kbase + 16 + lr <= qg)) ? s1[r] : -1e30f;
      float tm = fmaxf(a0, a1);
      tm = fmaxf(tm, __shfl_xor(tm, 1, 64));
      tm = fmaxf(tm, __shfl_xor(tm, 2, 64));
      tm = fmaxf(tm, __shfl_xor(tm, 4, 64));
      tm = fmaxf(tm, __shfl_xor(tm, 8, 64));
      float mn = fmaxf(m[r], tm);
      bool dead = (mn <= -1e29f);
      float sc = dead ? 1.f : __expf(m[r] - mn);
      float p0 = dead ? 0.f : __expf(a0 - mn);
      float p1 = dead ? 0.f : __expf(a1 - mn);
      l[r] = l[r] * sc + p0 + p1;   // per-lane partial; reduced in epilogue
      m[r] = mn;
      o0[r] *= sc; o1[r] *= sc; o2[r] *= sc; o3[r] *= sc;
      Ps[w][4 * lg + r][lr]      = (u16)bfr(p0);
      Ps[w][4 * lg + r][16 + lr] = (u16)bfr(p1);
    }

    asm volatile("s_waitcnt lgkmcnt(0)" ::: "memory");
    __builtin_amdgcn_sched_barrier(0);
    s8v pf  = *reinterpret_cast<const s8v*>(&Ps[w][lr][lg * 8]);
    const u16* vtb = vt + (size_t)(h * DH + lr) * S + kbase + lg * 8;
    s8v vf0 = *reinterpret_cast<const s8v*>(vtb);
    s8v vf1 = *reinterpret_cast<const s8v*>(vtb + (size_t)16 * S);
    s8v vf2 = *reinterpret_cast<const s8v*>(vtb + (size_t)32 * S);
    s8v vf3 = *reinterpret_cast<const s8v*>(vtb + (size_t)48 * S);
    o0 = __builtin_amdgcn_mfma_f32_16x16x32_bf16(pf, vf0, o0, 0, 0, 0);
    o1 = __builtin_amdgcn_mfma_f32_16x16x32_bf16(pf, vf1, o1, 0, 0, 0);
    o2 = __builtin_amdgcn_mfma_f32_16x16x32_bf16(pf, vf2, o2, 0, 0, 0);
    o3 = __builtin_amdgcn_mfma_f32_16x16x32_bf16(pf, vf3, o3, 0, 0, 0);
  }

  // waves 1-3 publish; wave 0 merges sequentially (deterministic) and finishes.
  if (w >= 1){
    #pragma unroll
    for (int r = 0; r < 4; ++r){
      Msh[w - 1][lane][r] = m[r];
      Lsh[w - 1][lane][r] = l[r];
      Osh[w - 1][0][lane][r] = o0[r];
      Osh[w - 1][1][lane][r] = o1[r];
      Osh[w - 1][2][lane][r] = o2[r];
      Osh[w - 1][3][lane][r] = o3[r];
    }
  }
  __syncthreads();
  if (w >= 1) return;

  #pragma unroll
  for (int i = 0; i < 3; ++i){
    #pragma unroll
    for (int r = 0; r < 4; ++r){
      float m1 = Msh[i][lane][r];
      float M  = fmaxf(m[r], m1);
      bool dead = (M <= -1e29f);
      float f0 = dead ? 1.f : __expf(m[r] - M);
      float f1 = dead ? 0.f : __expf(m1 - M);
      l[r]  = l[r]  * f0 + Lsh[i][lane][r]    * f1;
      o0[r] = o0[r] * f0 + Osh[i][0][lane][r] * f1;
      o1[r] = o1[r] * f0 + Osh[i][1][lane][r] * f1;
      o2[r] = o2[r] * f0 + Osh[i][2][lane][r] * f1;
      o3[r] = o3[r] * f0 + Osh[i][3][lane][r] * f1;
      m[r] = M;
    }
  }

  #pragma unroll
  for (int r = 0; r < 4; ++r){
    float lt = l[r];
    lt += __shfl_xor(lt, 1, 64);
    lt += __shfl_xor(lt, 2, 64);
    lt += __shfl_xor(lt, 4, 64);
    lt += __shfl_xor(lt, 8, 64);
    int qg = q0 + 4 * lg + r;
    u16* orow = ob + (size_t)qg * D + h * DH;
    if (lt <= 0.f){
      // fully-masked row: uniform softmax over ALL S -> V column mean.
      #pragma unroll
      for (int c4 = 0; c4 < 4; ++c4){
        const u16* vr = vt + (size_t)(h * DH + c4 * 16 + lr) * S;
        float s = 0.f;
        for (int j = 0; j < S; ++j) s += u2f(vr[j]);
        orow[c4 * 16 + lr] = (u16)bfr(s * (1.f / (float)S));
      }
    } else {
      float inv = 1.f / lt;
      orow[lr]      = (u16)bfr(o0[r] * inv);
      orow[16 + lr] = (u16)bfr(o1[r] * inv);
      orow[32 + lr] = (u16)bfr(o2[r] * inv);
      orow[48 + lr] = (u16)bfr(o3[r] * inv);
    }
  }
}

} // anonymous namespace

extern "C" void kernel_launch(void* const* d_in, const int* in_sizes, int n_in,
                              void* d_out, int out_size, void* d_ws, size_t ws_size,
                              hipStream_t stream)
{
  (void)n_in; (void)out_size; (void)ws_size;

  int I_tok=0, I_emb=1, I_pos=2, I_l1s=3, I_l1b=4, I_wq=5, I_wk=6, I_wv=7,
      I_wo=8, I_l2s=9, I_l2b=10, I_w1=11, I_b1=12, I_w2=13, I_b2=14,
      I_lfs=15, I_lfb=16, I_wout=17, I_bout=18;
  if (in_sizes[0] != S){
    I_b1=0;  I_b2=1;  I_bout=2; I_emb=3;  I_l1b=4; I_l1s=5;  I_l2b=6;
    I_l2s=7; I_lfb=8; I_lfs=9;  I_pos=10; I_tok=11; I_w1=12; I_w2=13;
    I_wk=14; I_wo=15; I_wout=16; I_wq=17; I_wv=18;
  }

  const int*   tokens = (const int*)d_in[I_tok];
  const float* emb  = (const float*)d_in[I_emb];
  const float* pos  = (const float*)d_in[I_pos];
  const float* ln1s = (const float*)d_in[I_l1s];
  const float* ln1b = (const float*)d_in[I_l1b];
  const float* wq   = (const float*)d_in[I_wq];
  const float* wk   = (const float*)d_in[I_wk];
  const float* wv   = (const float*)d_in[I_wv];
  const float* wo   = (const float*)d_in[I_wo];
  const float* ln2s = (const float*)d_in[I_l2s];
  const float* ln2b = (const float*)d_in[I_l2b];
  const float* w1   = (const float*)d_in[I_w1];
  const float* b1   = (const float*)d_in[I_b1];
  const float* w2   = (const float*)d_in[I_w2];
  const float* b2   = (const float*)d_in[I_b2];
  const float* lnfs = (const float*)d_in[I_lfs];
  const float* lnfb = (const float*)d_in[I_lfb];
  const float* wout = (const float*)d_in[I_wout];
  const float* bout = (const float*)d_in[I_bout];
  float* outp = (float*)d_out;

  // ws layout (round-21 verified):
  char* ws = (char*)d_ws;
  float* x    = (float*)(ws);
  u16*  hb    = (u16*)(ws + ((size_t)4  << 20));
  u16*  qkvb  = (u16*)(ws + ((size_t)6  << 20));
  u16*  ob    = (u16*)(ws + ((size_t)12 << 20));
  u16*  gb    = (u16*)(ws + ((size_t)14 << 20));
  u16*  vtb   = (u16*)(ws + ((size_t)14 << 20));   // overlays gb (transient)
  float* pWO  = (float*)(ws + ((size_t)14 << 20)); // overlays gb
  float* pW2  = (float*)(ws + ((size_t)6  << 20)); // overlays qkvb+ob
  u16*  wqkvT = (u16*)(ws + ((size_t)23 << 20));
  u16*  w1T   = (u16*)(ws + ((size_t)32 << 20));
  u16*  w2T   = (u16*)(ws + ((size_t)44 << 20));
  u16*  woT   = (u16*)(ws + ((size_t)56 << 20));
  u16*  woutT = (u16*)(ws + ((size_t)59 << 20));

  const size_t L512 = (size_t)512 * 512;
  const size_t LMLP = (size_t)512 * 2048;
  const size_t SM   = (size_t)S * 512;     // elements of one [2048][512] partial

  // weight transforms
  k_wt4<<<dim3(16, 16, 24), dim3(256), 0, stream>>>(wq, wk, wv, wo, wqkvT, woT);
  k_wt<<<dim3(64, 16, 6), dim3(256), 0, stream>>>(w1, w1T, 512, 2048, LMLP, LMLP);
  k_wt<<<dim3(16, 64, 6), dim3(256), 0, stream>>>(w2, w2T, 2048, 512, LMLP, LMLP);
  k_wt<<<dim3(8,  16, 1), dim3(256), 0, stream>>>(wout, woutT, 512, 256, 0, 0);

  k_embed<<<dim3(S), dim3(128), 0, stream>>>(tokens, emb, pos, x);

  for (int l = 0; l < NL; ++l){
    if (l == 0){
      k_lnr<0><<<dim3(S/4), dim3(256), 0, stream>>>(
          nullptr, nullptr, nullptr, x, ln1s, ln1b, hb);
    }
    // qkv: LDS-staged 128x64 tiles, grid (24,16)=384 blocks (r20 config)
    k_gsq<<<dim3(24, 16), dim3(256), 0, stream>>>(
        hb, wqkvT + (size_t)l * QS * 512, vtb, qkvb, 0.125f);
    // attention: split-KV x4, 4 waves per (head, 16 q-rows)
    k_mattn<<<dim3(S/16, H), dim3(256), 0, stream>>>(
        qkvb, qkvb + 512, vtb, tokens, ob);
    // wo: inter-block split-K=2; reduce fused into ln2
    k_gds<2,4><<<dim3(8, 64, 2), dim3(64), 0, stream>>>(
        ob, woT + (size_t)l * L512, pWO, 512, 512, 256);
    k_lnr<1><<<dim3(S/4), dim3(256), 0, stream>>>(
        pWO, pWO + SM, nullptr, x, ln2s + (size_t)l*D, ln2b + (size_t)l*D, hb);
    // w1: LDS-staged 128x64 tiles, grid (32,16)=512 blocks (r19 config)
    k_gs<1><<<dim3(32, 16), dim3(256), 0, stream>>>(
        hb, w1T + (size_t)l * LMLP, b1 + (size_t)l*MLPD, gb, MLPD, 512);
    // w2: inter-block split-K=2; reduce fused into next LN
    k_gds<2,4><<<dim3(8, 64, 2), dim3(64), 0, stream>>>(
        gb, w2T + (size_t)l * LMLP, pW2, 512, 2048, 1024);
    if (l < NL - 1){
      k_lnr<1><<<dim3(S/4), dim3(256), 0, stream>>>(
          pW2, pW2 + SM, b2 + (size_t)l*D, x,
          ln1s + (size_t)(l+1)*D, ln1b + (size_t)(l+1)*D, hb);
    } else {
      k_lnr<1><<<dim3(S/4), dim3(256), 0, stream>>>(
          pW2, pW2 + SM, b2 + (size_t)l*D, x, lnfs, lnfb, hb);
    }
  }

  // logits: 32x64 tiles (round-11 config)
  k_gd<2,4,3><<<dim3(4, 64), dim3(64), 0, stream>>>(
      hb, woutT, bout, outp, nullptr, VOC, 512, 1.f);
}

// Round 23
// 632.907 us; speedup vs baseline: 1.0111x; 1.0111x over previous
//
#include <hip/hip_runtime.h>
#include <hip/hip_bf16.h>
#include <cstdint>
#include <cstddef>

#define DEV __device__ __forceinline__

namespace {

constexpr int S    = 2048;
constexpr int D    = 512;
constexpr int H    = 8;
constexpr int DH   = 64;
constexpr int NL   = 6;
constexpr int MLPD = 2048;
constexpr int VOC  = 256;
constexpr int QS   = 1536;   // fused qkv row stride
constexpr float EPSF = 1e-6f;

typedef unsigned short u16;
typedef __attribute__((ext_vector_type(8))) short s8v;   // 8 x bf16 (4 VGPR)
typedef __attribute__((ext_vector_type(4))) float f4v;   // MFMA accum

DEV float u2f(u16 u){
  union { unsigned int i; float f; } t; t.i = ((unsigned int)u) << 16; return t.f;
}
DEV short bfr(float f){
  __hip_bfloat16 h = __float2bfloat16(f);
  short s; __builtin_memcpy(&s, &h, 2); return s;
}
// gelu_tanh(x) = 0.5x(1+tanh(z)) == x / (1 + e^{-2z}) exactly; __expf ~1ulp.
DEV float gelu_fast(float x){
  float z = 0.7978845608028654f * (x + 0.044715f * x * x * x);
  return x / (1.f + __expf(-2.f * z));
}
DEV void gll16(const u16* gp, u16* lp){
  __builtin_amdgcn_global_load_lds(
      (const __attribute__((address_space(1))) unsigned int*)gp,
      (__attribute__((address_space(3))) unsigned int*)lp, 16, 0, 0);
}

// ---------------- embedding + positional --------------------------------------
__global__ void k_embed(const int* __restrict__ tokens, const float* __restrict__ emb,
                        const float* __restrict__ pos, float* __restrict__ x){
  int s = blockIdx.x;
  int tok = (s == 0) ? 0 : tokens[s - 1];
  if (tok < 0) tok = 0; if (tok >= VOC) tok = VOC - 1;
  const float* er = emb + (size_t)tok * D;
  const float* pr = pos + (size_t)s * D;
  float* xr = x + (size_t)s * D;
  for (int d = threadIdx.x; d < D; d += blockDim.x)
    xr[d] = er[d] + pr[d];
}

// ------- fused split-K-reduce + residual + layernorm --------------------------
template<int HASP>
__global__ __launch_bounds__(256)
void k_lnr(const float* __restrict__ P0, const float* __restrict__ P1,
           const float* __restrict__ bias, float* __restrict__ x,
           const float* __restrict__ sc, const float* __restrict__ bi,
           u16* __restrict__ out)
{
  int s = blockIdx.x * 4 + (threadIdx.x >> 6), t = threadIdx.x & 63;
  size_t base = (size_t)s * D;
  float v[8]; float sum = 0.f, sq = 0.f;
  #pragma unroll
  for (int e = 0; e < 8; ++e){
    int d = t + 64 * e;
    size_t idx = base + d;
    float xv = x[idx];
    if (HASP){
      float bv = bias ? bias[d] : 0.f;
      xv += P0[idx] + P1[idx] + bv;
      x[idx] = xv;
    }
    v[e] = xv; sum += xv; sq += xv * xv;
  }
  #pragma unroll
  for (int off = 32; off >= 1; off >>= 1){
    sum += __shfl_down(sum, off, 64);
    sq  += __shfl_down(sq,  off, 64);
  }
  sum = __shfl(sum, 0, 64); sq = __shfl(sq, 0, 64);
  float mu  = sum * (1.f / (float)D);
  float var = sq * (1.f / (float)D) - mu * mu;
  float r = rsqrtf(var + EPSF);
  u16* orow = out + base;
  #pragma unroll
  for (int e = 0; e < 8; ++e){
    int d = t + 64 * e;
    orow[d] = (u16)bfr((v[e] - mu) * r * sc[d] + bi[d]);
  }
}

// ---------------- weight transpose+convert: fp32 [R][C] -> bf16 [C][R] --------
__global__ __launch_bounds__(256)
void k_wt(const float* __restrict__ src, u16* __restrict__ dst, int R, int C,
          size_t sStr, size_t dStr){
  src += (size_t)blockIdx.z * sStr;
  dst += (size_t)blockIdx.z * dStr;
  __shared__ float tb[32][33];
  int c0 = blockIdx.x * 32, r0 = blockIdx.y * 32;
  int tc = threadIdx.x & 31, tr8 = threadIdx.x >> 5;
  #pragma unroll
  for (int rr = 0; rr < 32; rr += 8)
    tb[rr + tr8][tc] = src[(size_t)(r0 + rr + tr8) * C + c0 + tc];
  __syncthreads();
  #pragma unroll
  for (int rr = 0; rr < 32; rr += 8)
    dst[(size_t)(c0 + rr + tr8) * R + r0 + tc] = (u16)bfr(tb[tc][rr + tr8]);
}

// ---- batched 512x512 transpose: z in [0,24) = family(z/6: wq,wk,wv,wo) x layer
__global__ __launch_bounds__(256)
void k_wt4(const float* __restrict__ wq, const float* __restrict__ wk,
           const float* __restrict__ wv, const float* __restrict__ wo,
           u16* __restrict__ wqkvT, u16* __restrict__ woT)
{
  const size_t L512 = (size_t)512 * 512;
  int fam = blockIdx.z / 6, l = blockIdx.z % 6;
  const float* src;
  u16* dst;
  if (fam == 0){ src = wq + (size_t)l * L512; dst = wqkvT + (size_t)l * QS * 512; }
  else if (fam == 1){ src = wk + (size_t)l * L512; dst = wqkvT + (size_t)l * QS * 512 + 512 * 512; }
  else if (fam == 2){ src = wv + (size_t)l * L512; dst = wqkvT + (size_t)l * QS * 512 + 1024 * 512; }
  else { src = wo + (size_t)l * L512; dst = woT + (size_t)l * L512; }
  __shared__ float tb[32][33];
  int c0 = blockIdx.x * 32, r0 = blockIdx.y * 32;
  int tc = threadIdx.x & 31, tr8 = threadIdx.x >> 5;
  #pragma unroll
  for (int rr = 0; rr < 32; rr += 8)
    tb[rr + tr8][tc] = src[(size_t)(r0 + rr + tr8) * 512 + c0 + tc];
  __syncthreads();
  #pragma unroll
  for (int rr = 0; rr < 32; rr += 8)
    dst[(size_t)(c0 + rr + tr8) * 512 + r0 + tc] = (u16)bfr(tb[tc][rr + tr8]);
}

// ================= direct-from-global MFMA GEMM (verified r10/r11) ============
template<int FM, int FN, int MODE>
__global__ __launch_bounds__(64)
void k_gd(const u16* __restrict__ A, const u16* __restrict__ Bt,
          const float* __restrict__ bias, float* __restrict__ Cf,
          u16* __restrict__ Cb, int N, int K, float alpha)
{
  const int nx = gridDim.x;
  const int nwg = nx * gridDim.y;
  int wg = blockIdx.y * nx + blockIdx.x;
  wg = (wg & 7) * (nwg >> 3) + (wg >> 3);        // XCD swizzle (nwg % 8 == 0)
  const int m0 = (wg / nx) * (FM * 16), n0 = (wg % nx) * (FN * 16);
  const int lane = threadIdx.x, lr = lane & 15, lg = lane >> 4;
  const u16* ap = A  + (size_t)(m0 + lr) * K + lg * 8;
  const u16* bp = Bt + (size_t)(n0 + lr) * K + lg * 8;
  f4v acc[FM][FN] = {};
  #pragma unroll 4
  for (int k0 = 0; k0 < K; k0 += 32){
    s8v af[FM], bf[FN];
    #pragma unroll
    for (int fi = 0; fi < FM; ++fi)
      af[fi] = *reinterpret_cast<const s8v*>(ap + (size_t)fi * 16 * K + k0);
    #pragma unroll
    for (int fj = 0; fj < FN; ++fj)
      bf[fj] = *reinterpret_cast<const s8v*>(bp + (size_t)fj * 16 * K + k0);
    #pragma unroll
    for (int fi = 0; fi < FM; ++fi)
      #pragma unroll
      for (int fj = 0; fj < FN; ++fj)
        acc[fi][fj] = __builtin_amdgcn_mfma_f32_16x16x32_bf16(af[fi], bf[fj], acc[fi][fj], 0, 0, 0);
  }
  #pragma unroll
  for (int fi = 0; fi < FM; ++fi)
    #pragma unroll
    for (int fj = 0; fj < FN; ++fj)
      #pragma unroll
      for (int r = 0; r < 4; ++r){
        int row = m0 + fi * 16 + lg * 4 + r;
        int col = n0 + fj * 16 + lr;
        size_t idx = (size_t)row * N + col;
        float v = acc[fi][fj][r];
        if (MODE == 1)      Cb[idx] = (u16)bfr(gelu_fast(v + bias[col]));
        else if (MODE == 2) Cf[idx] += v + (bias ? bias[col] : 0.f);
        else if (MODE == 3) Cf[idx] = v + bias[col];
        else {
          float al = (col < 512) ? alpha : 1.f;
          Cb[idx] = (u16)bfr(v * al);
        }
      }
}

// ===== LDS-staged GEMM, tile 128(M)x64(N), 4 waves (2x2 of 64x32) =============
// (verified r19: chunk-XOR swizzle, 2 blocks/CU.) MODE 1: gelu epilogue.
template<int MODE>
__global__ __launch_bounds__(256)
void k_gs(const u16* __restrict__ A, const u16* __restrict__ Bt,
          const float* __restrict__ bias, u16* __restrict__ Cb,
          int N, int K)
{
  __shared__ __align__(16) u16 As[128 * 32];
  __shared__ __align__(16) u16 Bs[64 * 32];
  const int nx = gridDim.x;
  const int nwg = nx * gridDim.y;
  int wg = blockIdx.y * nx + blockIdx.x;
  wg = (wg & 7) * (nwg >> 3) + (wg >> 3);        // XCD swizzle (nwg % 8 == 0)
  const int m0 = (wg / nx) * 128, n0 = (wg % nx) * 64;
  const int w = threadIdx.x >> 6, lane = threadIdx.x & 63;
  const int lr = lane & 15, lg = lane >> 4;
  const int wr = w >> 1, wc = w & 1;
  const int srow = lane >> 2, scd = lane & 3;
  const int swA0 = ((srow) ^ (srow >> 2)) & 3;
  f4v acc[4][2] = {};
  for (int k0 = 0; k0 < K; k0 += 32){
    __syncthreads();
    #pragma unroll
    for (int j = w; j < 8; j += 4){
      int row = j * 16 + srow;
      int g = scd ^ swA0;
      gll16(A + (size_t)(m0 + row) * K + k0 + g * 8, As + j * 512);
    }
    {
      int row = w * 16 + srow;
      int g = scd ^ swA0;
      gll16(Bt + (size_t)(n0 + row) * K + k0 + g * 8, Bs + w * 512);
    }
    asm volatile("s_waitcnt vmcnt(0)" ::: "memory");
    __syncthreads();
    s8v af[4], bf[2];
    #pragma unroll
    for (int fi = 0; fi < 4; ++fi){
      int row = wr * 64 + fi * 16 + lr;
      int slot = lg ^ ((row ^ (row >> 2)) & 3);
      af[fi] = *reinterpret_cast<const s8v*>(As + row * 32 + slot * 8);
    }
    #pragma unroll
    for (int fj = 0; fj < 2; ++fj){
      int row = wc * 32 + fj * 16 + lr;
      int slot = lg ^ ((row ^ (row >> 2)) & 3);
      bf[fj] = *reinterpret_cast<const s8v*>(Bs + row * 32 + slot * 8);
    }
    #pragma unroll
    for (int fi = 0; fi < 4; ++fi)
      #pragma unroll
      for (int fj = 0; fj < 2; ++fj)
        acc[fi][fj] = __builtin_amdgcn_mfma_f32_16x16x32_bf16(af[fi], bf[fj], acc[fi][fj], 0, 0, 0);
  }
  #pragma unroll
  for (int fi = 0; fi < 4; ++fi)
    #pragma unroll
    for (int fj = 0; fj < 2; ++fj)
      #pragma unroll
      for (int r = 0; r < 4; ++r){
        int row = m0 + wr * 64 + fi * 16 + lg * 4 + r;
        int col = n0 + wc * 32 + fj * 16 + lr;
        float v = acc[fi][fj][r];
        if (MODE == 1) Cb[(size_t)row * N + col] = (u16)bfr(gelu_fast(v + bias[col]));
      }
}

// ===== staged qkv: k_gs body + verified MODE-4 epilogue (verified r20) ========
__global__ __launch_bounds__(256)
void k_gsq(const u16* __restrict__ A, const u16* __restrict__ Bt,
           u16* __restrict__ vt, u16* __restrict__ Cb, float alpha)
{
  constexpr int K = 512, N = QS;
  __shared__ __align__(16) u16 As[128 * 32];
  __shared__ __align__(16) u16 Bs[64 * 32];
  const int nx = gridDim.x;
  const int nwg = nx * gridDim.y;
  int wg = blockIdx.y * nx + blockIdx.x;
  wg = (wg & 7) * (nwg >> 3) + (wg >> 3);        // XCD swizzle (384 % 8 == 0)
  const int m0 = (wg / nx) * 128, n0 = (wg % nx) * 64;
  const int w = threadIdx.x >> 6, lane = threadIdx.x & 63;
  const int lr = lane & 15, lg = lane >> 4;
  const int wr = w >> 1, wc = w & 1;
  const int srow = lane >> 2, scd = lane & 3;
  const int swA0 = ((srow) ^ (srow >> 2)) & 3;
  f4v acc[4][2] = {};
  for (int k0 = 0; k0 < K; k0 += 32){
    __syncthreads();
    #pragma unroll
    for (int j = w; j < 8; j += 4){
      int row = j * 16 + srow;
      int g = scd ^ swA0;
      gll16(A + (size_t)(m0 + row) * K + k0 + g * 8, As + j * 512);
    }
    {
      int row = w * 16 + srow;
      int g = scd ^ swA0;
      gll16(Bt + (size_t)(n0 + row) * K + k0 + g * 8, Bs + w * 512);
    }
    asm volatile("s_waitcnt vmcnt(0)" ::: "memory");
    __syncthreads();
    s8v af[4], bf[2];
    #pragma unroll
    for (int fi = 0; fi < 4; ++fi){
      int row = wr * 64 + fi * 16 + lr;
      int slot = lg ^ ((row ^ (row >> 2)) & 3);
      af[fi] = *reinterpret_cast<const s8v*>(As + row * 32 + slot * 8);
    }
    #pragma unroll
    for (int fj = 0; fj < 2; ++fj){
      int row = wc * 32 + fj * 16 + lr;
      int slot = lg ^ ((row ^ (row >> 2)) & 3);
      bf[fj] = *reinterpret_cast<const s8v*>(Bs + row * 32 + slot * 8);
    }
    #pragma unroll
    for (int fi = 0; fi < 4; ++fi)
      #pragma unroll
      for (int fj = 0; fj < 2; ++fj)
        acc[fi][fj] = __builtin_amdgcn_mfma_f32_16x16x32_bf16(af[fi], bf[fj], acc[fi][fj], 0, 0, 0);
  }
  #pragma unroll
  for (int fi = 0; fi < 4; ++fi)
    #pragma unroll
    for (int fj = 0; fj < 2; ++fj)
      #pragma unroll
      for (int r = 0; r < 4; ++r){
        int row = m0 + wr * 64 + fi * 16 + lg * 4 + r;
        int col = n0 + wc * 32 + fj * 16 + lr;
        float v = acc[fi][fj][r];
        if (col < 512){
          Cb[(size_t)row * N + col] = (u16)bfr(v * alpha);
        } else if (col < 1024){
          Cb[(size_t)row * N + col] = (u16)bfr(v);
        } else {
          vt[(size_t)(col - 1024) * S + row] = (u16)bfr(v);   // V^T only
        }
      }
}

// ---- inter-block split-K variant (verified r11): fp32 partials ---------------
template<int FM, int FN>
__global__ __launch_bounds__(64)
void k_gds(const u16* __restrict__ A, const u16* __restrict__ Bt,
           float* __restrict__ P, int N, int K, int KC)
{
  const int nx = gridDim.x;
  const int nwg = nx * gridDim.y;
  const int M = gridDim.y * (FM * 16);
  int wg = blockIdx.y * nx + blockIdx.x;
  wg = (wg & 7) * (nwg >> 3) + (wg >> 3);        // XCD swizzle (nwg % 8 == 0)
  const int m0 = (wg / nx) * (FM * 16), n0 = (wg % nx) * (FN * 16);
  const int z = blockIdx.z;
  const int lane = threadIdx.x, lr = lane & 15, lg = lane >> 4;
  const u16* ap = A  + (size_t)(m0 + lr) * K + z * KC + lg * 8;
  const u16* bp = Bt + (size_t)(n0 + lr) * K + z * KC + lg * 8;
  P += (size_t)z * M * N;
  f4v acc[FM][FN] = {};
  #pragma unroll 4
  for (int k0 = 0; k0 < KC; k0 += 32){
    s8v af[FM], bf[FN];
    #pragma unroll
    for (int fi = 0; fi < FM; ++fi)
      af[fi] = *reinterpret_cast<const s8v*>(ap + (size_t)fi * 16 * K + k0);
    #pragma unroll
    for (int fj = 0; fj < FN; ++fj)
      bf[fj] = *reinterpret_cast<const s8v*>(bp + (size_t)fj * 16 * K + k0);
    #pragma unroll
    for (int fi = 0; fi < FM; ++fi)
      #pragma unroll
      for (int fj = 0; fj < FN; ++fj)
        acc[fi][fj] = __builtin_amdgcn_mfma_f32_16x16x32_bf16(af[fi], bf[fj], acc[fi][fj], 0, 0, 0);
  }
  #pragma unroll
  for (int fi = 0; fi < FM; ++fi)
    #pragma unroll
    for (int fj = 0; fj < FN; ++fj)
      #pragma unroll
      for (int r = 0; r < 4; ++r){
        int row = m0 + fi * 16 + lg * 4 + r;
        int col = n0 + fj * 16 + lr;
        P[(size_t)row * N + col] = acc[fi][fj][r];
      }
}

// -------- split-KV barrier-light flash attention: 2 waves per (head, 16 q) ----
// (verified r21: best measured config.) Wave w handles tiles tt = w, w+2, ...;
// wave 1 publishes (m, l, o) via LDS; wave 0 does the flash merge + epilogue.
__global__ __launch_bounds__(128)
void k_mattn(const u16* __restrict__ qp_, const u16* __restrict__ kp_,
             const u16* __restrict__ vt, const int* __restrict__ tokens,
             u16* __restrict__ ob)
{
  const int q0 = (gridDim.x - 1 - blockIdx.x) * 16;   // heavy-first
  const int h  = blockIdx.y;
  const int B  = q0 >> 7;
  const int w  = threadIdx.x >> 6;
  const int lane = threadIdx.x & 63, lr = lane & 15, lg = lane >> 4;

  __shared__ __align__(16) u16 Ps[2][16][40];
  __shared__ float Msh[64][4], Lsh[64][4], Osh[4][64][4];

  const u16* qrow = qp_ + (size_t)(q0 + lr) * QS + h * DH;
  s8v qf0 = *reinterpret_cast<const s8v*>(qrow + lg * 8);
  s8v qf1 = *reinterpret_cast<const s8v*>(qrow + 32 + lg * 8);

  f4v o0 = {}, o1 = {}, o2 = {}, o3 = {};
  float m[4] = {-1e30f, -1e30f, -1e30f, -1e30f};
  float l[4] = {0.f, 0.f, 0.f, 0.f};

  const int ntiles = B + ((q0 & 127) >> 5) + 1;

  for (int tt = w; tt < ntiles; tt += 2){
    int kbase; bool causal;
    if (tt < B){ kbase = tt * 128 + 96; causal = false; }
    else       { kbase = B * 128 + (tt - B) * 32; causal = (kbase + 31 > q0); }

    f4v s0 = {}, s1 = {};
    const u16* k0p = kp_ + (size_t)(kbase + lr) * QS + h * DH;
    const u16* k1p = kp_ + (size_t)(kbase + 16 + lr) * QS + h * DH;
    s8v kf;
    kf = *reinterpret_cast<const s8v*>(k0p + lg * 8);
    s0 = __builtin_amdgcn_mfma_f32_16x16x32_bf16(qf0, kf, s0, 0, 0, 0);
    kf = *reinterpret_cast<const s8v*>(k0p + 32 + lg * 8);
    s0 = __builtin_amdgcn_mfma_f32_16x16x32_bf16(qf1, kf, s0, 0, 0, 0);
    kf = *reinterpret_cast<const s8v*>(k1p + lg * 8);
    s1 = __builtin_amdgcn_mfma_f32_16x16x32_bf16(qf0, kf, s1, 0, 0, 0);
    kf = *reinterpret_cast<const s8v*>(k1p + 32 + lg * 8);
    s1 = __builtin_amdgcn_mfma_f32_16x16x32_bf16(qf1, kf, s1, 0, 0, 0);

    const int tok0 = tokens[kbase + lr] > 0;
    const int tok1 = tokens[kbase + 16 + lr] > 0;
    #pragma unroll
    for (int r = 0; r < 4; ++r){
      int qg = q0 + 4 * lg + r;
      float a0 = (tok0 && (!causal || kbase + lr <= qg))      ? s0[r] : -1e30f;
      float a1 = (tok1 && (!causal || kbase + 16 + lr <= qg)) ? s1[r] : -1e30f;
      float tm = fmaxf(a0, a1);
      tm = fmaxf(tm, __shfl_xor(tm, 1, 64));
      tm = fmaxf(tm, __shfl_xor(tm, 2, 64));
      tm = fmaxf(tm, __shfl_xor(tm, 4, 64));
      tm = fmaxf(tm, __shfl_xor(tm, 8, 64));
      float mn = fmaxf(m[r], tm);
      bool dead = (mn <= -1e29f);
      float sc = dead ? 1.f : __expf(m[r] - mn);
      float p0 = dead ? 0.f : __expf(a0 - mn);
      float p1 = dead ? 0.f : __expf(a1 - mn);
      l[r] = l[r] * sc + p0 + p1;   // per-lane partial; reduced in epilogue
      m[r] = mn;
      o0[r] *= sc; o1[r] *= sc; o2[r] *= sc; o3[r] *= sc;
      Ps[w][4 * lg + r][lr]      = (u16)bfr(p0);
      Ps[w][4 * lg + r][16 + lr] = (u16)bfr(p1);
    }

    asm volatile("s_waitcnt lgkmcnt(0)" ::: "memory");
    __builtin_amdgcn_sched_barrier(0);
    s8v pf  = *reinterpret_cast<const s8v*>(&Ps[w][lr][lg * 8]);
    const u16* vtb = vt + (size_t)(h * DH + lr) * S + kbase + lg * 8;
    s8v vf0 = *reinterpret_cast<const s8v*>(vtb);
    s8v vf1 = *reinterpret_cast<const s8v*>(vtb + (size_t)16 * S);
    s8v vf2 = *reinterpret_cast<const s8v*>(vtb + (size_t)32 * S);
    s8v vf3 = *reinterpret_cast<const s8v*>(vtb + (size_t)48 * S);
    o0 = __builtin_amdgcn_mfma_f32_16x16x32_bf16(pf, vf0, o0, 0, 0, 0);
    o1 = __builtin_amdgcn_mfma_f32_16x16x32_bf16(pf, vf1, o1, 0, 0, 0);
    o2 = __builtin_amdgcn_mfma_f32_16x16x32_bf16(pf, vf2, o2, 0, 0, 0);
    o3 = __builtin_amdgcn_mfma_f32_16x16x32_bf16(pf, vf3, o3, 0, 0, 0);
  }

  // wave 1 publishes its state; wave 0 merges (flash combine) and finishes.
  if (w == 1){
    #pragma unroll
    for (int r = 0; r < 4; ++r){
      Msh[lane][r] = m[r];
      Lsh[lane][r] = l[r];
      Osh[0][lane][r] = o0[r];
      Osh[1][lane][r] = o1[r];
      Osh[2][lane][r] = o2[r];
      Osh[3][lane][r] = o3[r];
    }
  }
  __syncthreads();
  if (w == 1) return;

  #pragma unroll
  for (int r = 0; r < 4; ++r){
    float m1 = Msh[lane][r];
    float M  = fmaxf(m[r], m1);
    bool dead = (M <= -1e29f);
    float f0 = dead ? 1.f : __expf(m[r] - M);
    float f1 = dead ? 0.f : __expf(m1 - M);
    l[r]  = l[r]  * f0 + Lsh[lane][r]    * f1;
    o0[r] = o0[r] * f0 + Osh[0][lane][r] * f1;
    o1[r] = o1[r] * f0 + Osh[1][lane][r] * f1;
    o2[r] = o2[r] * f0 + Osh[2][lane][r] * f1;
    o3[r] = o3[r] * f0 + Osh[3][lane][r] * f1;
    m[r] = M;
  }

  #pragma unroll
  for (int r = 0; r < 4; ++r){
    float lt = l[r];
    lt += __shfl_xor(lt, 1, 64);
    lt += __shfl_xor(lt, 2, 64);
    lt += __shfl_xor(lt, 4, 64);
    lt += __shfl_xor(lt, 8, 64);
    int qg = q0 + 4 * lg + r;
    u16* orow = ob + (size_t)qg * D + h * DH;
    if (lt <= 0.f){
      // fully-masked row: uniform softmax over ALL S -> V column mean.
      #pragma unroll
      for (int c4 = 0; c4 < 4; ++c4){
        const u16* vr = vt + (size_t)(h * DH + c4 * 16 + lr) * S;
        float s = 0.f;
        for (int j = 0; j < S; ++j) s += u2f(vr[j]);
        orow[c4 * 16 + lr] = (u16)bfr(s * (1.f / (float)S));
      }
    } else {
      float inv = 1.f / lt;
      orow[lr]      = (u16)bfr(o0[r] * inv);
      orow[16 + lr] = (u16)bfr(o1[r] * inv);
      orow[32 + lr] = (u16)bfr(o2[r] * inv);
      orow[48 + lr] = (u16)bfr(o3[r] * inv);
    }
  }
}

} // anonymous namespace

extern "C" void kernel_launch(void* const* d_in, const int* in_sizes, int n_in,
                              void* d_out, int out_size, void* d_ws, size_t ws_size,
                              hipStream_t stream)
{
  (void)n_in; (void)out_size; (void)ws_size;

  int I_tok=0, I_emb=1, I_pos=2, I_l1s=3, I_l1b=4, I_wq=5, I_wk=6, I_wv=7,
      I_wo=8, I_l2s=9, I_l2b=10, I_w1=11, I_b1=12, I_w2=13, I_b2=14,
      I_lfs=15, I_lfb=16, I_wout=17, I_bout=18;
  if (in_sizes[0] != S){
    I_b1=0;  I_b2=1;  I_bout=2; I_emb=3;  I_l1b=4; I_l1s=5;  I_l2b=6;
    I_l2s=7; I_lfb=8; I_lfs=9;  I_pos=10; I_tok=11; I_w1=12; I_w2=13;
    I_wk=14; I_wo=15; I_wout=16; I_wq=17; I_wv=18;
  }

  const int*   tokens = (const int*)d_in[I_tok];
  const float* emb  = (const float*)d_in[I_emb];
  const float* pos  = (const float*)d_in[I_pos];
  const float* ln1s = (const float*)d_in[I_l1s];
  const float* ln1b = (const float*)d_in[I_l1b];
  const float* wq   = (const float*)d_in[I_wq];
  const float* wk   = (const float*)d_in[I_wk];
  const float* wv   = (const float*)d_in[I_wv];
  const float* wo   = (const float*)d_in[I_wo];
  const float* ln2s = (const float*)d_in[I_l2s];
  const float* ln2b = (const float*)d_in[I_l2b];
  const float* w1   = (const float*)d_in[I_w1];
  const float* b1   = (const float*)d_in[I_b1];
  const float* w2   = (const float*)d_in[I_w2];
  const float* b2   = (const float*)d_in[I_b2];
  const float* lnfs = (const float*)d_in[I_lfs];
  const float* lnfb = (const float*)d_in[I_lfb];
  const float* wout = (const float*)d_in[I_wout];
  const float* bout = (const float*)d_in[I_bout];
  float* outp = (float*)d_out;

  // ws layout (round-21 verified):
  char* ws = (char*)d_ws;
  float* x    = (float*)(ws);
  u16*  hb    = (u16*)(ws + ((size_t)4  << 20));
  u16*  qkvb  = (u16*)(ws + ((size_t)6  << 20));
  u16*  ob    = (u16*)(ws + ((size_t)12 << 20));
  u16*  gb    = (u16*)(ws + ((size_t)14 << 20));
  u16*  vtb   = (u16*)(ws + ((size_t)14 << 20));   // overlays gb (transient)
  float* pWO  = (float*)(ws + ((size_t)14 << 20)); // overlays gb
  float* pW2  = (float*)(ws + ((size_t)6  << 20)); // overlays qkvb+ob
  u16*  wqkvT = (u16*)(ws + ((size_t)23 << 20));
  u16*  w1T   = (u16*)(ws + ((size_t)32 << 20));
  u16*  w2T   = (u16*)(ws + ((size_t)44 << 20));
  u16*  woT   = (u16*)(ws + ((size_t)56 << 20));
  u16*  woutT = (u16*)(ws + ((size_t)59 << 20));

  const size_t L512 = (size_t)512 * 512;
  const size_t LMLP = (size_t)512 * 2048;
  const size_t SM   = (size_t)S * 512;     // elements of one [2048][512] partial

  // weight transforms
  k_wt4<<<dim3(16, 16, 24), dim3(256), 0, stream>>>(wq, wk, wv, wo, wqkvT, woT);
  k_wt<<<dim3(64, 16, 6), dim3(256), 0, stream>>>(w1, w1T, 512, 2048, LMLP, LMLP);
  k_wt<<<dim3(16, 64, 6), dim3(256), 0, stream>>>(w2, w2T, 2048, 512, LMLP, LMLP);
  k_wt<<<dim3(8,  16, 1), dim3(256), 0, stream>>>(wout, woutT, 512, 256, 0, 0);

  k_embed<<<dim3(S), dim3(128), 0, stream>>>(tokens, emb, pos, x);

  for (int l = 0; l < NL; ++l){
    if (l == 0){
      k_lnr<0><<<dim3(S/4), dim3(256), 0, stream>>>(
          nullptr, nullptr, nullptr, x, ln1s, ln1b, hb);
    }
    // qkv: LDS-staged 128x64 tiles, grid (24,16)=384 blocks (r20 config)
    k_gsq<<<dim3(24, 16), dim3(256), 0, stream>>>(
        hb, wqkvT + (size_t)l * QS * 512, vtb, qkvb, 0.125f);
    // attention: split-KV, 2 waves per (head, 16 q-rows) (r21 config)
    k_mattn<<<dim3(S/16, H), dim3(128), 0, stream>>>(
        qkvb, qkvb + 512, vtb, tokens, ob);
    // wo: inter-block split-K=2; reduce fused into ln2
    k_gds<2,4><<<dim3(8, 64, 2), dim3(64), 0, stream>>>(
        ob, woT + (size_t)l * L512, pWO, 512, 512, 256);
    k_lnr<1><<<dim3(S/4), dim3(256), 0, stream>>>(
        pWO, pWO + SM, nullptr, x, ln2s + (size_t)l*D, ln2b + (size_t)l*D, hb);
    // w1: LDS-staged 128x64 tiles, grid (32,16)=512 blocks (r19 config)
    k_gs<1><<<dim3(32, 16), dim3(256), 0, stream>>>(
        hb, w1T + (size_t)l * LMLP, b1 + (size_t)l*MLPD, gb, MLPD, 512);
    // w2: inter-block split-K=2; reduce fused into next LN
    k_gds<2,4><<<dim3(8, 64, 2), dim3(64), 0, stream>>>(
        gb, w2T + (size_t)l * LMLP, pW2, 512, 2048, 1024);
    if (l < NL - 1){
      k_lnr<1><<<dim3(S/4), dim3(256), 0, stream>>>(
          pW2, pW2 + SM, b2 + (size_t)l*D, x,
          ln1s + (size_t)(l+1)*D, ln1b + (size_t)(l+1)*D, hb);
    } else {
      k_lnr<1><<<dim3(S/4), dim3(256), 0, stream>>>(
          pW2, pW2 + SM, b2 + (size_t)l*D, x, lnfs, lnfb, hb);
    }
  }

  // logits: 32x64 tiles (round-11 config)
  k_gd<2,4,3><<<dim3(4, 64), dim3(64), 0, stream>>>(
      hb, woutT, bout, outp, nullptr, VOC, 512, 1.f);
}